// Round 7
// baseline (309.417 us; speedup 1.0000x reference)
//
#include <hip/hip_runtime.h>
#include <math.h>

// FineGrainLoss: B=96, n1=196 (image tokens), n2=77 (text tokens), d=512.
#define BB 96
#define N1 196
#define N2 77
#define DD 512

#define IMGN (BB * N1 * DD)
#define TXTN (BB * N2 * DD)

// R16 = R4 fat-wave geometry + R6 tiled-h16 staging + coalesced convert.
// WHY: R6 slot model (3,275 cyc): staging 2,255 (gload_lds of 48 KB/slot
// at ~21.8 B/cyc) + LDS reads 1,590 (132 b128 at 85 B/cyc) + VALU 1,050 —
// partial overlap. Fat waves (4 waves, 2x2 grid, strips {7,6} x bt-half)
// cut LDS reads to 92 KB/slot (B frags re-read 2x not 4x): the compute
// that must hide under the staging floor shrinks 30%. R4 proved this
// geometry spill-free (100 VGPR) but was staging-bound at the time
// (scattered 64-B rows, 11.9 B/cyc); tiled h16 removed that constraint.
// Tiles: 1-KB contiguous [16 rows x 32 k], cell = lq*16+lm, layout
// [bi][13 strips][16 kc] then [bt][5 cts][16 kc].
// LESSONS CARRIED: (R11) never force occupancy via launch_bounds (acc
// spills -> WRITE_SIZE balloons). (R14) no reg-staging (+36 regs spills).
#define ATILES 13
#define NTILES 24              // 23 real + 1 dummy (exactly 6 tiles/wave)
#define BUFH (NTILES * 512)    // _Float16 per buffer (24,576 B)

#define TA_TILES (BB * 13 * 16)            // 19,968 A tiles
#define TB_TILES (BB * 5 * 16)             //  7,680 B tiles
#define NT_TILES (TA_TILES + TB_TILES)     // 27,648 tiles (28.3 MB)

#define NSTRIPS_A (BB * 13)    // 1,248
#define NSTRIPS_B (BB * 5)     //   480
#define NSTRIPS   (NSTRIPS_A + NSTRIPS_B)

typedef _Float16 f16x8 __attribute__((ext_vector_type(8)));  // 8 f16 (4 VGPR)
typedef float f4v __attribute__((ext_vector_type(4)));       // MFMA C/D

typedef unsigned int __attribute__((address_space(1))) as1_uint;
typedef unsigned int __attribute__((address_space(3))) as3_uint;

__device__ __forceinline__ void gload_lds16(const void* g, void* l) {
    __builtin_amdgcn_global_load_lds((const as1_uint*)g, (as3_uint*)l, 16, 0, 0);
}

// fp32 -> f16 convert + TILE pass, coalesced BOTH sides.
// One 256-thread block per 16-row strip: source rows are consecutive ->
// read 16x512 fp32 CONTIGUOUS (32 KB); transpose via padded LDS; write
// the strip's 16 tiles = 16 KB CONTIGUOUS (tiles [..][kc] adjacent).
// (R6's convert did scattered 16-B writes -> this was ~2x slower.)
__global__ __launch_bounds__(256) void convert_tiled_kernel(
    const float* __restrict__ img, const float* __restrict__ txt,
    _Float16* __restrict__ dst)
{
    __shared__ _Float16 sh[16 * 520];   // row pad 520 (1040 B = 65x16B)
    const int sid = blockIdx.x;
    const int tid = threadIdx.x;
    const float* base;
    int rowbase, rmax, tile0;
    if (sid < NSTRIPS_A) {
        const int bi = sid / 13, s = sid % 13;
        base = img + (size_t)bi * N1 * DD;
        rowbase = s * 16; rmax = N1 - 1;
        tile0 = sid * 16;
    } else {
        const int bs = sid - NSTRIPS_A;
        const int bt = bs / 5, ct = bs % 5;
        base = txt + (size_t)bt * N2 * DD;
        rowbase = ct * 16; rmax = N2 - 1;
        tile0 = TA_TILES + bs * 16;
    }
#pragma unroll
    for (int it = 0; it < 8; ++it) {
        const int u  = it * 256 + tid;   // 0..2047 float4-units
        const int r  = u >> 7;           // 0..15
        const int c4 = u & 127;          // float4 within row
        int q = rowbase + r; q = q > rmax ? rmax : q;
        float4 v = *(const float4*)(base + (size_t)q * DD + c4 * 4);
        union { _Float16 h[4]; uint2 u2; } o;
        o.h[0] = (_Float16)v.x; o.h[1] = (_Float16)v.y;
        o.h[2] = (_Float16)v.z; o.h[3] = (_Float16)v.w;
        *(uint2*)(sh + r * 520 + c4 * 4) = o.u2;
    }
    __syncthreads();
#pragma unroll
    for (int it = 0; it < 4; ++it) {
        const int w  = it * 256 + tid;   // 0..1023 16B-units
        const int kc = w >> 6;
        const int c  = w & 63;           // cell = lq*16+lm consumed by MFMA
        const int r16 = c & 15, k8 = c >> 4;
        uint4 val = *(const uint4*)(sh + r16 * 520 + kc * 32 + k8 * 8);
        *(uint4*)(dst + (size_t)(tile0 + kc) * 512 + c * 8) = val;
    }
}

// One K=32 sub-step: strips [SG0, SG0+NS) x 5 cts of bt-half H.
// A strip s at tile s; B ct of half H at tile ATILES + H*5 + ct.
template <int SG0, int NS, int H>
__device__ __forceinline__ void compute_sub(const f16x8* __restrict__ fr,
                                            f4v* __restrict__ acc, int lane) {
    f16x8 b[5];
#pragma unroll
    for (int ct = 0; ct < 5; ++ct)
        b[ct] = fr[(ATILES + H * 5 + ct) * 64 + lane];
#pragma unroll
    for (int i = 0; i < NS; ++i) {
        f16x8 a = fr[(SG0 + i) * 64 + lane];
#pragma unroll
        for (int ct = 0; ct < 5; ++ct)
            acc[i * 5 + ct] = __builtin_amdgcn_mfma_f32_16x16x32_f16(
                a, b[ct], acc[i * 5 + ct], 0, 0, 0);
    }
}

// Reduction partials. C/D layout: col = lane&15, row = (lane>>4)*4 + reg.
// rp[H*208 + q]: per-bt-half rowmax (each (H, strip) owned by one wave).
// cp[g*160 + H*80 + col]: colmax partial per strip-group (g = 0..1).
template <int SG0, int NS, int H>
__device__ __forceinline__ void reduce_phase1(const f4v* __restrict__ acc,
                                              int g, int lq, int lm,
                                              float* __restrict__ rp,
                                              float* __restrict__ cp) {
    float colm[5];
#pragma unroll
    for (int ct = 0; ct < 5; ++ct) colm[ct] = -INFINITY;
#pragma unroll
    for (int i = 0; i < NS; ++i) {
        const int s = SG0 + i;
        float rowm[4] = {-INFINITY, -INFINITY, -INFINITY, -INFINITY};
        bool rows_ok = (s != 12) || (lq == 0);   // rows >=196 are clamp-dups
#pragma unroll
        for (int ct = 0; ct < 5; ++ct) {
            f4v a = acc[i * 5 + ct];
            bool col_ok = (ct != 4) || (lm < N2 - 64);   // cols >=77 dups
            float cm = fmaxf(fmaxf(a[0], a[1]), fmaxf(a[2], a[3]));
            colm[ct] = fmaxf(colm[ct], rows_ok ? cm : -INFINITY);
#pragma unroll
            for (int r = 0; r < 4; ++r)
                rowm[r] = fmaxf(rowm[r], col_ok ? a[r] : -INFINITY);
        }
#pragma unroll
        for (int r = 0; r < 4; ++r) {
            float m = rowm[r];
            m = fmaxf(m, __shfl_xor(m, 1));
            m = fmaxf(m, __shfl_xor(m, 2));
            m = fmaxf(m, __shfl_xor(m, 4));
            m = fmaxf(m, __shfl_xor(m, 8));
            if (lm == 0) rp[H * 208 + s * 16 + lq * 4 + r] = m;
        }
    }
#pragma unroll
    for (int ct = 0; ct < 5; ++ct) {
        float m = colm[ct];
        m = fmaxf(m, __shfl_xor(m, 16));
        m = fmaxf(m, __shfl_xor(m, 32));
        if (lq == 0) cp[g * 160 + H * 80 + ct * 16 + lm] = m;
    }
}

// One block per (bi, btPair): S[208x160] = img[bi].(txt[bt0]|txt[bt1])^T.
// 256 threads = 4 waves in a 2x2 grid: strip-groups {7,6} x bt-half.
// __launch_bounds__(256,2): total-reg cap 256/wave; demand ~200 (acc 140
// + frags/addr, measured 100 arch-VGPR in R4). Do NOT raise min-waves.
template <bool PRE>
__global__ __launch_bounds__(256, 2) void sim_mfma_kernel(
    const float* __restrict__ imgF, const float* __restrict__ txtF,
    const _Float16* __restrict__ h16,   // TILED (see convert_tiled_kernel)
    float* __restrict__ i2t, float* __restrict__ t2i)
{
    // ---- XCD-locality swizzle (4608 blocks = 8 xcd x 12 bi x 48 btPairs) ----
    const int id  = blockIdx.x;
    const int xcd = id & 7;
    const int lid = id >> 3;           // 0..575
    const int w   = lid % 48;
    const int btq = lid / 48;          // 0..11
    const int btp = btq * 4 + (w & 3); // 0..47
    const int bi  = xcd * 12 + (w >> 2);
    const int bt0 = btp * 2;

    const int tid = threadIdx.x;
    const int wave = tid >> 6, lane = tid & 63;
    const int lm = lane & 15;
    const int lq = lane >> 4;
    const int g = wave >> 1;           // strip-group 0..1
    // const int h = wave & 1;         // bt-half (baked into templates)

    __shared__ __align__(16) _Float16 lds[3 * BUFH];   // 73,728 B
    // epilogue scratch in buffer 2: last compute (kc=15) reads buffer 0;
    // buffer 2's last readers (compute(14)) were separated by barrier-B(14)
    // and barrier-B(15) precedes the reduction writes.
    float* scratch = (float*)(lds + 2 * BUFH);
    float* rp   = scratch;             // 416: [half][208] rowmax
    float* cp   = scratch + 416;       // 320: [g][160] colmax partials
    float* sws  = scratch + 736;       // 4
    float* scol = scratch + 740;       // 160

    // ---- staging descriptors ----
    // Thread stages cell `lane` of tile T = 4j + wave, j=0..5 (24 tiles,
    // exactly 6 per wave). PRE: h16 tiled — off = tileBase*512 + lane*8;
    // stage adds kc*512 (adjacent kc tiles -> contiguous 1-KB reads).
    int off[6];
    const float* fsrc[6];
#pragma unroll
    for (int j = 0; j < 6; ++j) {
        const int T = 4 * j + wave;
        if constexpr (PRE) {
            int t;
            if (T < ATILES) {
                t = (bi * 13 + T) * 16;
            } else if (T < 23) {
                const int ct = T - ATILES;      // 0..9
                const int bt = bt0 + (ct >= 5);
                t = TA_TILES + (bt * 5 + (ct % 5)) * 16;
            } else {
                t = 0;   // dummy: re-reads A tile 0, content never used
            }
            off[j] = t * 512 + lane * 8;
        } else {
            int o;
            bool isA = true;
            if (T < ATILES) {
                int q = T * 16 + lm; q = q > (N1 - 1) ? (N1 - 1) : q;
                o = (bi * N1 + q) * DD + lq * 8;
            } else if (T < 23) {
                isA = false;
                int ct = T - ATILES;
                int bt = bt0 + (ct >= 5);
                int r = (ct % 5) * 16 + lm; r = r > (N2 - 1) ? (N2 - 1) : r;
                o = (bt * N2 + r) * DD + lq * 8;
            } else {
                o = lq * 8;
            }
            off[j] = o;
            fsrc[j] = isA ? imgF : txtF;
        }
    }

    // async staging of K32 chunk kc into buffer b (6 contiguous 1-KB reads)
    auto stage = [&](int kc, int b) {
        const int k0 = kc * 512;
#pragma unroll
        for (int j = 0; j < 6; ++j)
            gload_lds16(h16 + off[j] + k0,
                        lds + (b * NTILES + 4 * j + wave) * 512);
    };

    f4v acc[35];   // waves 0,1 (7-strip group): 35; waves 2,3: 30 (tail dead)
#pragma unroll
    for (int i = 0; i < 35; ++i) acc[i] = (f4v){0.f, 0.f, 0.f, 0.f};

    auto do_compute = [&](const f16x8* fr) {
        if (wave == 0)      compute_sub<0, 7, 0>(fr, acc, lane);
        else if (wave == 1) compute_sub<0, 7, 1>(fr, acc, lane);
        else if (wave == 2) compute_sub<7, 6, 0>(fr, acc, lane);
        else                compute_sub<7, 6, 1>(fr, acc, lane);
    };

    if constexpr (PRE) {
        // ---- K loop: 16 steps of BK=32, 3 buffers, prefetch distance 2.
        // Counted vmcnt: each wave holds 6 loads/step, <=18 in flight;
        // vmcnt(12) waits only for the step about to be computed, so the
        // two younger steps' DMA stays in flight across both barriers.
        // Barrier A: all waves' loads for buf kc landed.
        // Barrier B: all waves done reading buf kc%3 before stage(kc+3)
        // (issued at iter kc+1 top) overwrites it.
        stage(0, 0);
        stage(1, 1);
#pragma unroll 1
        for (int kc = 0; kc < 16; ++kc) {
            if (kc < 14) {
                stage(kc + 2, (kc + 2) % 3);
                asm volatile("s_waitcnt vmcnt(12)" ::: "memory");
            } else if (kc == 14) {
                asm volatile("s_waitcnt vmcnt(6)" ::: "memory");
            } else {
                asm volatile("s_waitcnt vmcnt(0)" ::: "memory");
            }
            __builtin_amdgcn_s_barrier();          // A
            asm volatile("" ::: "memory");
            do_compute((const f16x8*)(lds + (kc % 3) * BUFH));
            asm volatile("" ::: "memory");
            __builtin_amdgcn_s_barrier();          // B
        }
    } else {
        // correctness fallback (workspace too small): sync single-buffer
#pragma unroll 1
        for (int kc = 0; kc < 16; ++kc) {
            __syncthreads();
            const int k0 = kc * 32;
#pragma unroll
            for (int j = 0; j < 6; ++j) {
                const int T = 4 * j + wave;
                if (T < 23) {
                    float4 v0 = *(const float4*)(fsrc[j] + off[j] + k0);
                    float4 v1 = *(const float4*)(fsrc[j] + off[j] + k0 + 4);
                    union { f16x8 f; uint4 u; } o;
                    o.f[0] = (_Float16)v0.x; o.f[1] = (_Float16)v0.y;
                    o.f[2] = (_Float16)v0.z; o.f[3] = (_Float16)v0.w;
                    o.f[4] = (_Float16)v1.x; o.f[5] = (_Float16)v1.y;
                    o.f[6] = (_Float16)v1.z; o.f[7] = (_Float16)v1.w;
                    ((uint4*)lds)[T * 64 + lane] = o.u;
                }
            }
            __syncthreads();
            do_compute((const f16x8*)lds);
        }
        __syncthreads();
    }

    // ---- fused reductions (buffer-2 scratch; no race with K loop) ----
    if (wave == 0)      reduce_phase1<0, 7, 0>(acc, g, lq, lm, rp, cp);
    else if (wave == 1) reduce_phase1<0, 7, 1>(acc, g, lq, lm, rp, cp);
    else if (wave == 2) reduce_phase1<7, 6, 0>(acc, g, lq, lm, rp, cp);
    else                reduce_phase1<7, 6, 1>(acc, g, lq, lm, rp, cp);
    __syncthreads();

    // i2t: mean over q<196 of rowmax, per bt-half.
    // wave w: half h = w&1, row-segment sseg = w>>1 (rows sseg*128 + lane
    // and +64). qa is always <196; qb needs the guard.
    {
        const int h = wave & 1;
        const int sseg = wave >> 1;
        const int qa = sseg * 128 + lane;
        const int qb = qa + 64;
        float v = rp[h * 208 + qa];
        if (qb < N1) v += rp[h * 208 + qb];
        v += __shfl_xor(v, 1);  v += __shfl_xor(v, 2);  v += __shfl_xor(v, 4);
        v += __shfl_xor(v, 8);  v += __shfl_xor(v, 16); v += __shfl_xor(v, 32);
        if (lane == 0) sws[wave] = v;
    }
    // colmax merge across the 2 strip-groups
    if (tid < 160) scol[tid] = fmaxf(cp[tid], cp[160 + tid]);
    __syncthreads();
    if (tid == 0)
        i2t[bi * BB + bt0] = (sws[0] + sws[2]) * (1.f / (float)N1);
    if (tid == 1)
        i2t[bi * BB + bt0 + 1] = (sws[1] + sws[3]) * (1.f / (float)N1);
    // t2i: mean over r<77 of colmax; wave0 -> bt0 (cols 0-79), wave1 -> bt1.
    if (wave < 2) {
        const float* c = scol + wave * 80;
        float cv = c[lane] + ((lane < N2 - 64) ? c[64 + lane] : 0.f);
        cv += __shfl_xor(cv, 1);  cv += __shfl_xor(cv, 2);  cv += __shfl_xor(cv, 4);
        cv += __shfl_xor(cv, 8);  cv += __shfl_xor(cv, 16); cv += __shfl_xor(cv, 32);
        if (lane == 0)
            t2i[(bt0 + wave) * BB + bi] = cv * (1.f / (float)N2);
    }
}

// CE with arange labels over both [B,B] logit matrices.
__global__ __launch_bounds__(256) void ce_kernel(
    const float* __restrict__ i2t, const float* __restrict__ t2i,
    float* __restrict__ out)
{
    const int tid = threadIdx.x;
    const int wid = tid >> 6;
    const int lane = tid & 63;

    float contrib = 0.f;
    if (tid < 2 * BB) {
        const float* M = (tid < BB) ? i2t : t2i;
        const int b = (tid < BB) ? tid : tid - BB;
        const float* row = M + b * BB;
        float mx = row[0];
#pragma unroll 1
        for (int c = 1; c < BB; ++c) mx = fmaxf(mx, row[c]);
        float s = 0.f;
#pragma unroll 1
        for (int c = 0; c < BB; ++c) s += expf(row[c] - mx);
        float lse = mx + logf(s);
        contrib = row[b] - lse;
    }
    contrib += __shfl_xor(contrib, 1);
    contrib += __shfl_xor(contrib, 2);
    contrib += __shfl_xor(contrib, 4);
    contrib += __shfl_xor(contrib, 8);
    contrib += __shfl_xor(contrib, 16);
    contrib += __shfl_xor(contrib, 32);

    __shared__ float s_part[4];
    if (lane == 0) s_part[wid] = contrib;
    __syncthreads();
    if (tid == 0) {
        float total = s_part[0] + s_part[1] + s_part[2] + s_part[3];
        out[0] = -total * (1.f / (float)(2 * BB));
    }
}

extern "C" void kernel_launch(void* const* d_in, const int* in_sizes, int n_in,
                              void* d_out, int out_size, void* d_ws, size_t ws_size,
                              hipStream_t stream) {
    const float* img = (const float*)d_in[0];   // [96,196,512] fp32
    const float* txt = (const float*)d_in[1];   // [96,77,512] fp32
    float* i2t = (float*)d_ws;                  // [96,96]
    float* t2i = i2t + BB * BB;                 // [96,96]

    const size_t conv_off = 2 * BB * BB * sizeof(float);   // 16B-aligned
    const size_t need = conv_off + (size_t)NT_TILES * 512 * sizeof(_Float16);

    const int nblocks = BB * (BB / 2);   // 4608 = (bi, btPair)
    if (ws_size >= need) {
        _Float16* h16 = (_Float16*)((char*)d_ws + conv_off);
        convert_tiled_kernel<<<NSTRIPS, 256, 0, stream>>>(img, txt, h16);
        sim_mfma_kernel<true><<<nblocks, 256, 0, stream>>>(img, txt, h16, i2t, t2i);
    } else {
        sim_mfma_kernel<false><<<nblocks, 256, 0, stream>>>(img, txt, nullptr, i2t, t2i);
    }
    ce_kernel<<<1, 256, 0, stream>>>(i2t, t2i, (float*)d_out);
}

// Round 8
// 303.888 us; speedup vs baseline: 1.0182x; 1.0182x over previous
//
#include <hip/hip_runtime.h>
#include <math.h>

// FineGrainLoss: B=96, n1=196 (image tokens), n2=77 (text tokens), d=512.
#define BB 96
#define N1 196
#define N2 77
#define DD 512

#define IMGN (BB * N1 * DD)
#define TXTN (BB * N2 * DD)

// R17 BIG-TILE: block = (bi, btQuad) covering 208 x 320 (13 A strips x
// 4 bt x 5 ct tiles), 1024 threads = 16 waves in a 4x4 grid:
// strip-groups {4,3,3,3} x bt-columns. Per-wave acc = NS*5 <= 20 f4v —
// IDENTICAL register profile to R6 (the 16-waves/CU sweet spot; R7 proved
// halving waves to 8 costs 11% even with 30% less LDS traffic).
// WHY: staged volume = M*N*1024*(1/T_M+1/T_N): 208x160 -> 1.74 GB (R6,
// floor 132 us at 21.8 B/cyc/CU); 208x320 -> 1.22 GB (-30%) at the SAME
// per-wave registers and SAME waves/CU. Staging/slot 48 KB -> 33 KB at
// equal MFMA work. Schedule = R1/R6-proven 3-buffer prefetch-2 counted
// vmcnt (wave 0 stages 3 tiles/step, others 2 -> vmcnt 6/4).
// Tiled h16 (R15): 1-KB tiles [16 rows x 32 k], cell = lq*16+lm, layout
// [bi][13 strips][16 kc] then [bt][5 cts][16 kc] -> contiguous 1-KB reads.
// LESSONS: (R11) never force occupancy via launch_bounds (acc spills ->
// WRITE_SIZE balloons). (R14) no reg-staging (+36 regs spills). (R7) don't
// trade waves for per-wave width.
#define ATILES 13
#define BTILES 20
#define NTILES 33              // 13 A + 20 B, no dummy
#define BUFH (NTILES * 512)    // _Float16 per buffer (16,896 B)

#define TA_TILES (BB * 13 * 16)            // 19,968 A tiles
#define TB_TILES (BB * 5 * 16)             //  7,680 B tiles
#define NT_TILES (TA_TILES + TB_TILES)     // 27,648 tiles (28.3 MB)

#define NSTRIPS_A (BB * 13)    // 1,248
#define NSTRIPS_B (BB * 5)     //   480
#define NSTRIPS   (NSTRIPS_A + NSTRIPS_B)

typedef _Float16 f16x8 __attribute__((ext_vector_type(8)));  // 8 f16 (4 VGPR)
typedef float f4v __attribute__((ext_vector_type(4)));       // MFMA C/D

typedef unsigned int __attribute__((address_space(1))) as1_uint;
typedef unsigned int __attribute__((address_space(3))) as3_uint;

__device__ __forceinline__ void gload_lds16(const void* g, void* l) {
    __builtin_amdgcn_global_load_lds((const as1_uint*)g, (as3_uint*)l, 16, 0, 0);
}

// fp32 -> f16 convert + TILE pass, coalesced BOTH sides (R16's version).
// One 256-thread block per 16-row strip: read 16x512 fp32 contiguous,
// transpose via padded LDS, write the strip's 16 tiles (16 KB) contiguous.
__global__ __launch_bounds__(256) void convert_tiled_kernel(
    const float* __restrict__ img, const float* __restrict__ txt,
    _Float16* __restrict__ dst)
{
    __shared__ _Float16 sh[16 * 520];   // row pad 520 (1040 B = 65x16B)
    const int sid = blockIdx.x;
    const int tid = threadIdx.x;
    const float* base;
    int rowbase, rmax, tile0;
    if (sid < NSTRIPS_A) {
        const int bi = sid / 13, s = sid % 13;
        base = img + (size_t)bi * N1 * DD;
        rowbase = s * 16; rmax = N1 - 1;
        tile0 = sid * 16;
    } else {
        const int bs = sid - NSTRIPS_A;
        const int bt = bs / 5, ct = bs % 5;
        base = txt + (size_t)bt * N2 * DD;
        rowbase = ct * 16; rmax = N2 - 1;
        tile0 = TA_TILES + bs * 16;
    }
#pragma unroll
    for (int it = 0; it < 8; ++it) {
        const int u  = it * 256 + tid;   // 0..2047 float4-units
        const int r  = u >> 7;           // 0..15
        const int c4 = u & 127;          // float4 within row
        int q = rowbase + r; q = q > rmax ? rmax : q;
        float4 v = *(const float4*)(base + (size_t)q * DD + c4 * 4);
        union { _Float16 h[4]; uint2 u2; } o;
        o.h[0] = (_Float16)v.x; o.h[1] = (_Float16)v.y;
        o.h[2] = (_Float16)v.z; o.h[3] = (_Float16)v.w;
        *(uint2*)(sh + r * 520 + c4 * 4) = o.u2;
    }
    __syncthreads();
#pragma unroll
    for (int it = 0; it < 4; ++it) {
        const int w  = it * 256 + tid;   // 0..1023 16B-units
        const int kc = w >> 6;
        const int c  = w & 63;           // cell = lq*16+lm consumed by MFMA
        const int r16 = c & 15, k8 = c >> 4;
        uint4 val = *(const uint4*)(sh + r16 * 520 + kc * 32 + k8 * 8);
        *(uint4*)(dst + (size_t)(tile0 + kc) * 512 + c * 8) = val;
    }
}

// One K=32 sub-step: strips [SG0, SG0+NS) x 5 cts of bt-column CG.
// A strip s at tile s; B ct of column CG at tile 13 + CG*5 + ct.
template <int SG0, int NS, int CG>
__device__ __forceinline__ void compute_sub(const f16x8* __restrict__ fr,
                                            f4v* __restrict__ acc, int lane) {
    f16x8 b[5];
#pragma unroll
    for (int ct = 0; ct < 5; ++ct)
        b[ct] = fr[(ATILES + CG * 5 + ct) * 64 + lane];
#pragma unroll
    for (int i = 0; i < NS; ++i) {
        f16x8 a = fr[(SG0 + i) * 64 + lane];
#pragma unroll
        for (int ct = 0; ct < 5; ++ct)
            acc[i * 5 + ct] = __builtin_amdgcn_mfma_f32_16x16x32_f16(
                a, b[ct], acc[i * 5 + ct], 0, 0, 0);
    }
}

// Reduction partials. C/D layout: col = lane&15, row = (lane>>4)*4 + reg.
// rp[CG*208 + q]: per-bt-column rowmax (wave (g,CG) owns strips of g — the
// full rowmax over bt's 77 cols is exactly this wave's 5 cts).
// cp[g*320 + CG*80 + col]: colmax partial per strip-group, merged over g.
template <int SG0, int NS, int CG>
__device__ __forceinline__ void reduce_phase1(const f4v* __restrict__ acc,
                                              int g, int lq, int lm,
                                              float* __restrict__ rp,
                                              float* __restrict__ cp) {
    float colm[5];
#pragma unroll
    for (int ct = 0; ct < 5; ++ct) colm[ct] = -INFINITY;
#pragma unroll
    for (int i = 0; i < NS; ++i) {
        const int s = SG0 + i;
        float rowm[4] = {-INFINITY, -INFINITY, -INFINITY, -INFINITY};
        bool rows_ok = (s != 12) || (lq == 0);   // rows >=196 are clamp-dups
#pragma unroll
        for (int ct = 0; ct < 5; ++ct) {
            f4v a = acc[i * 5 + ct];
            bool col_ok = (ct != 4) || (lm < N2 - 64);   // cols >=77 dups
            float cm = fmaxf(fmaxf(a[0], a[1]), fmaxf(a[2], a[3]));
            colm[ct] = fmaxf(colm[ct], rows_ok ? cm : -INFINITY);
#pragma unroll
            for (int r = 0; r < 4; ++r)
                rowm[r] = fmaxf(rowm[r], col_ok ? a[r] : -INFINITY);
        }
#pragma unroll
        for (int r = 0; r < 4; ++r) {
            float m = rowm[r];
            m = fmaxf(m, __shfl_xor(m, 1));
            m = fmaxf(m, __shfl_xor(m, 2));
            m = fmaxf(m, __shfl_xor(m, 4));
            m = fmaxf(m, __shfl_xor(m, 8));
            if (lm == 0) rp[CG * 208 + s * 16 + lq * 4 + r] = m;
        }
    }
#pragma unroll
    for (int ct = 0; ct < 5; ++ct) {
        float m = colm[ct];
        m = fmaxf(m, __shfl_xor(m, 16));
        m = fmaxf(m, __shfl_xor(m, 32));
        if (lq == 0) cp[g * 320 + CG * 80 + ct * 16 + lm] = m;
    }
}

// One block per (bi, btQuad): S[208x320] = img[bi].(txt[bt0..bt0+3])^T.
// 1024 threads = 16 waves, 4x4 grid: strip-groups {4,3,3,3} x bt-columns.
// __launch_bounds__(1024,4): 16 waves = 4/SIMD, reg cap 128 — the exact
// cap R6 proved spill-free at this per-wave profile (acc 20 f4v, ~64 VGPR).
template <bool PRE>
__global__ __launch_bounds__(1024, 4) void sim_mfma_kernel(
    const float* __restrict__ imgF, const float* __restrict__ txtF,
    const _Float16* __restrict__ h16,   // TILED (see convert_tiled_kernel)
    float* __restrict__ i2t, float* __restrict__ t2i)
{
    // ---- XCD-locality swizzle (2304 blocks = 8 xcd x 12 bi x 24 btQuads) ----
    const int id  = blockIdx.x;
    const int xcd = id & 7;
    const int lid = id >> 3;             // 0..287
    const int bi  = xcd * 12 + lid / 24;
    const int btq = lid % 24;
    const int bt0 = btq * 4;

    const int tid = threadIdx.x;
    const int wave = tid >> 6, lane = tid & 63;
    const int lm = lane & 15;
    const int lq = lane >> 4;
    const int g  = wave >> 2;            // strip-group 0..3
    // const int cg = wave & 3;          // bt-column (baked into templates)

    __shared__ __align__(16) _Float16 lds[3 * BUFH];   // 101,376 B
    // epilogue scratch aliases buffer 0: compute(15) reads buffer 15%3=0,
    // but barrier B at the end of iter 15 separates all its readers from
    // the reduction writes below.
    float* scratch = (float*)lds;
    float* rp   = scratch;               //  832: [cg][208] rowmax
    float* cp   = scratch + 832;         // 1280: [g][cg*80+col] colmax part
    float* scol = scratch + 2112;        //  320: merged colmax

    // ---- staging descriptors ----
    // Thread stages cell `lane` of tile T = 16j + wave, j=0..2 (33 tiles:
    // wave 0 stages 3, waves 1-15 stage 2). T<13 -> A strip T; else B:
    // jj=T-13, cg=jj/5, ct=jj%5, bt=bt0+cg. h16 tiled: off = tile*512 +
    // lane*8; stage adds kc*512 (adjacent kc tiles -> contiguous 1 KB).
    int off[3];
    const float* fsrc[3];
#pragma unroll
    for (int j = 0; j < 3; ++j) {
        const int T = 16 * j + wave;
        if constexpr (PRE) {
            int t = 0;
            if (T < ATILES) {
                t = (bi * 13 + T) * 16;
            } else if (T < NTILES) {
                const int jj = T - ATILES;     // 0..19
                const int cgj = jj / 5, ct = jj % 5;
                const int bt = bt0 + cgj;
                t = TA_TILES + (bt * 5 + ct) * 16;
            }
            off[j] = t * 512 + lane * 8;
        } else {
            int o = 0;
            bool isA = true;
            if (T < ATILES) {
                int q = T * 16 + lm; q = q > (N1 - 1) ? (N1 - 1) : q;
                o = (bi * N1 + q) * DD + lq * 8;
            } else if (T < NTILES) {
                isA = false;
                const int jj = T - ATILES;
                const int cgj = jj / 5, ct = jj % 5;
                const int bt = bt0 + cgj;
                int r = ct * 16 + lm; r = r > (N2 - 1) ? (N2 - 1) : r;
                o = (bt * N2 + r) * DD + lq * 8;
            }
            off[j] = o;
            fsrc[j] = isA ? imgF : txtF;
        }
    }

    // async staging of K32 chunk kc into buffer b (contiguous 1-KB reads)
    auto stage = [&](int kc, int b) {
        const int k0 = kc * 512;
#pragma unroll
        for (int j = 0; j < 3; ++j)
            if (16 * j + wave < NTILES)   // wave-uniform guard
                gload_lds16(h16 + off[j] + k0,
                            lds + (b * NTILES + 16 * j + wave) * 512);
    };

    f4v acc[20];   // strip-group 0 waves: 20; others: 15 (tail dead)
#pragma unroll
    for (int i = 0; i < 20; ++i) acc[i] = (f4v){0.f, 0.f, 0.f, 0.f};

    auto do_compute = [&](const f16x8* fr) {
        if      (wave ==  0) compute_sub<0, 4, 0>(fr, acc, lane);
        else if (wave ==  1) compute_sub<0, 4, 1>(fr, acc, lane);
        else if (wave ==  2) compute_sub<0, 4, 2>(fr, acc, lane);
        else if (wave ==  3) compute_sub<0, 4, 3>(fr, acc, lane);
        else if (wave ==  4) compute_sub<4, 3, 0>(fr, acc, lane);
        else if (wave ==  5) compute_sub<4, 3, 1>(fr, acc, lane);
        else if (wave ==  6) compute_sub<4, 3, 2>(fr, acc, lane);
        else if (wave ==  7) compute_sub<4, 3, 3>(fr, acc, lane);
        else if (wave ==  8) compute_sub<7, 3, 0>(fr, acc, lane);
        else if (wave ==  9) compute_sub<7, 3, 1>(fr, acc, lane);
        else if (wave == 10) compute_sub<7, 3, 2>(fr, acc, lane);
        else if (wave == 11) compute_sub<7, 3, 3>(fr, acc, lane);
        else if (wave == 12) compute_sub<10, 3, 0>(fr, acc, lane);
        else if (wave == 13) compute_sub<10, 3, 1>(fr, acc, lane);
        else if (wave == 14) compute_sub<10, 3, 2>(fr, acc, lane);
        else                 compute_sub<10, 3, 3>(fr, acc, lane);
    };

    if constexpr (PRE) {
        // ---- K loop: 16 steps of BK=32, 3 buffers, prefetch distance 2.
        // Counted vmcnt per wave (wave 0 holds 3 loads/step, others 2):
        // steady state 3 steps in flight -> wait oldest: vmcnt(2L).
        // Barrier A: all waves' loads for buf kc landed.
        // Barrier B: all waves done reading buf kc%3 before stage(kc+3)
        // (issued at iter kc+1 top) overwrites it.
        stage(0, 0);
        stage(1, 1);
#pragma unroll 1
        for (int kc = 0; kc < 16; ++kc) {
            if (kc < 14) {
                stage(kc + 2, (kc + 2) % 3);
                if (wave == 0) asm volatile("s_waitcnt vmcnt(6)" ::: "memory");
                else           asm volatile("s_waitcnt vmcnt(4)" ::: "memory");
            } else if (kc == 14) {
                if (wave == 0) asm volatile("s_waitcnt vmcnt(3)" ::: "memory");
                else           asm volatile("s_waitcnt vmcnt(2)" ::: "memory");
            } else {
                asm volatile("s_waitcnt vmcnt(0)" ::: "memory");
            }
            __builtin_amdgcn_s_barrier();          // A
            asm volatile("" ::: "memory");
            do_compute((const f16x8*)(lds + (kc % 3) * BUFH));
            asm volatile("" ::: "memory");
            __builtin_amdgcn_s_barrier();          // B
        }
    } else {
        // correctness fallback (workspace too small): sync single-buffer
#pragma unroll 1
        for (int kc = 0; kc < 16; ++kc) {
            __syncthreads();
            const int k0 = kc * 32;
#pragma unroll
            for (int j = 0; j < 3; ++j) {
                const int T = 16 * j + wave;
                if (T < NTILES) {
                    float4 v0 = *(const float4*)(fsrc[j] + off[j] + k0);
                    float4 v1 = *(const float4*)(fsrc[j] + off[j] + k0 + 4);
                    union { f16x8 f; uint4 u; } o;
                    o.f[0] = (_Float16)v0.x; o.f[1] = (_Float16)v0.y;
                    o.f[2] = (_Float16)v0.z; o.f[3] = (_Float16)v0.w;
                    o.f[4] = (_Float16)v1.x; o.f[5] = (_Float16)v1.y;
                    o.f[6] = (_Float16)v1.z; o.f[7] = (_Float16)v1.w;
                    ((uint4*)lds)[T * 64 + lane] = o.u;
                }
            }
            __syncthreads();
            do_compute((const f16x8*)lds);
        }
        __syncthreads();
    }

    // ---- fused reductions (buffer-0 scratch; barrier-separated) ----
    if      (wave ==  0) reduce_phase1<0, 4, 0>(acc, g, lq, lm, rp, cp);
    else if (wave ==  1) reduce_phase1<0, 4, 1>(acc, g, lq, lm, rp, cp);
    else if (wave ==  2) reduce_phase1<0, 4, 2>(acc, g, lq, lm, rp, cp);
    else if (wave ==  3) reduce_phase1<0, 4, 3>(acc, g, lq, lm, rp, cp);
    else if (wave ==  4) reduce_phase1<4, 3, 0>(acc, g, lq, lm, rp, cp);
    else if (wave ==  5) reduce_phase1<4, 3, 1>(acc, g, lq, lm, rp, cp);
    else if (wave ==  6) reduce_phase1<4, 3, 2>(acc, g, lq, lm, rp, cp);
    else if (wave ==  7) reduce_phase1<4, 3, 3>(acc, g, lq, lm, rp, cp);
    else if (wave ==  8) reduce_phase1<7, 3, 0>(acc, g, lq, lm, rp, cp);
    else if (wave ==  9) reduce_phase1<7, 3, 1>(acc, g, lq, lm, rp, cp);
    else if (wave == 10) reduce_phase1<7, 3, 2>(acc, g, lq, lm, rp, cp);
    else if (wave == 11) reduce_phase1<7, 3, 3>(acc, g, lq, lm, rp, cp);
    else if (wave == 12) reduce_phase1<10, 3, 0>(acc, g, lq, lm, rp, cp);
    else if (wave == 13) reduce_phase1<10, 3, 1>(acc, g, lq, lm, rp, cp);
    else if (wave == 14) reduce_phase1<10, 3, 2>(acc, g, lq, lm, rp, cp);
    else                 reduce_phase1<10, 3, 3>(acc, g, lq, lm, rp, cp);
    __syncthreads();

    // i2t: waves 0-3, one per bt-column: mean over q<196 of rp[cg][q].
    if (wave < 4) {
        const float* r = rp + wave * 208;
        float v = r[lane] + r[64 + lane] + r[128 + lane]
                + ((lane < 4) ? r[192 + lane] : 0.f);
        v += __shfl_xor(v, 1);  v += __shfl_xor(v, 2);  v += __shfl_xor(v, 4);
        v += __shfl_xor(v, 8);  v += __shfl_xor(v, 16); v += __shfl_xor(v, 32);
        if (lane == 0) i2t[bi * BB + bt0 + wave] = v * (1.f / (float)N1);
    }
    // colmax merge across the 4 strip-groups
    if (tid < 320)
        scol[tid] = fmaxf(fmaxf(cp[tid], cp[320 + tid]),
                          fmaxf(cp[640 + tid], cp[960 + tid]));
    __syncthreads();
    // t2i: waves 4-7, one per bt-column: mean over r<77 of merged colmax.
    if (wave >= 4 && wave < 8) {
        const int c4 = wave - 4;
        const float* c = scol + c4 * 80;
        float cv = c[lane] + ((lane < N2 - 64) ? c[64 + lane] : 0.f);
        cv += __shfl_xor(cv, 1);  cv += __shfl_xor(cv, 2);  cv += __shfl_xor(cv, 4);
        cv += __shfl_xor(cv, 8);  cv += __shfl_xor(cv, 16); cv += __shfl_xor(cv, 32);
        if (lane == 0)
            t2i[(bt0 + c4) * BB + bi] = cv * (1.f / (float)N2);
    }
}

// CE with arange labels over both [B,B] logit matrices.
__global__ __launch_bounds__(256) void ce_kernel(
    const float* __restrict__ i2t, const float* __restrict__ t2i,
    float* __restrict__ out)
{
    const int tid = threadIdx.x;
    const int wid = tid >> 6;
    const int lane = tid & 63;

    float contrib = 0.f;
    if (tid < 2 * BB) {
        const float* M = (tid < BB) ? i2t : t2i;
        const int b = (tid < BB) ? tid : tid - BB;
        const float* row = M + b * BB;
        float mx = row[0];
#pragma unroll 1
        for (int c = 1; c < BB; ++c) mx = fmaxf(mx, row[c]);
        float s = 0.f;
#pragma unroll 1
        for (int c = 0; c < BB; ++c) s += expf(row[c] - mx);
        float lse = mx + logf(s);
        contrib = row[b] - lse;
    }
    contrib += __shfl_xor(contrib, 1);
    contrib += __shfl_xor(contrib, 2);
    contrib += __shfl_xor(contrib, 4);
    contrib += __shfl_xor(contrib, 8);
    contrib += __shfl_xor(contrib, 16);
    contrib += __shfl_xor(contrib, 32);

    __shared__ float s_part[4];
    if (lane == 0) s_part[wid] = contrib;
    __syncthreads();
    if (tid == 0) {
        float total = s_part[0] + s_part[1] + s_part[2] + s_part[3];
        out[0] = -total * (1.f / (float)(2 * BB));
    }
}

extern "C" void kernel_launch(void* const* d_in, const int* in_sizes, int n_in,
                              void* d_out, int out_size, void* d_ws, size_t ws_size,
                              hipStream_t stream) {
    const float* img = (const float*)d_in[0];   // [96,196,512] fp32
    const float* txt = (const float*)d_in[1];   // [96,77,512] fp32
    float* i2t = (float*)d_ws;                  // [96,96]
    float* t2i = i2t + BB * BB;                 // [96,96]

    const size_t conv_off = 2 * BB * BB * sizeof(float);   // 16B-aligned
    const size_t need = conv_off + (size_t)NT_TILES * 512 * sizeof(_Float16);

    const int nblocks = BB * (BB / 4);   // 2304 = (bi, btQuad)
    if (ws_size >= need) {
        _Float16* h16 = (_Float16*)((char*)d_ws + conv_off);
        convert_tiled_kernel<<<NSTRIPS, 256, 0, stream>>>(img, txt, h16);
        sim_mfma_kernel<true><<<nblocks, 1024, 0, stream>>>(img, txt, h16, i2t, t2i);
    } else {
        sim_mfma_kernel<false><<<nblocks, 1024, 0, stream>>>(img, txt, nullptr, i2t, t2i);
    }
    ce_kernel<<<1, 256, 0, stream>>>(i2t, t2i, (float*)d_out);
}

// Round 9
// 302.900 us; speedup vs baseline: 1.0215x; 1.0033x over previous
//
#include <hip/hip_runtime.h>
#include <math.h>

// FineGrainLoss: B=96, n1=196 (image tokens), n2=77 (text tokens), d=512.
#define BB 96
#define N1 196
#define N2 77
#define DD 512

#define IMGN (BB * N1 * DD)
#define TXTN (BB * N2 * DD)

// R18 = R17 big-tile with the XCD swizzle FIXED (bi fast, btq slow).
// R17 post-mortem: geometry was fine (sentinels clean) but the swizzle
// made 32 co-resident blocks/XCD span all 24 btq -> B working set 7.7 MB
// >> 4 MB L2 -> FETCH_SIZE 47->292 MB, staging fell off the L2 path.
// Corrected: consecutive lids vary bi (12 values, A=2.5 MB stays hot),
// btq advances every 12 blocks (B in-flight ~1 MB) -> ~3.4 MB < 4 MB L2.
// Geometry: block = (bi, btQuad) covering 208 x 320; 1024 thr = 16 waves
// in 4x4 grid (strip-groups {4,3,3,3} x bt-columns); per-wave acc <= 20
// f4v = R6's proven spill-free profile; 16 waves/CU.
// Staged volume 1.22 GB (-30% vs R6's 1.74 GB at 208x160).
// Tiled h16 (R15): 1-KB tiles [16 rows x 32 k], cell = lq*16+lm, layout
// [bi][13 strips][16 kc] then [bt][5 cts][16 kc] -> contiguous 1-KB reads.
// LESSONS: (R11) never force occupancy via launch_bounds (acc spills ->
// WRITE_SIZE balloons). (R14) no reg-staging (+36 regs spills). (R7) don't
// trade waves for per-wave width. (R17) co-resident working set must fit
// the 4 MB per-XCD L2 — watch FETCH_SIZE.
#define ATILES 13
#define BTILES 20
#define NTILES 33              // 13 A + 20 B, no dummy
#define BUFH (NTILES * 512)    // _Float16 per buffer (16,896 B)

#define TA_TILES (BB * 13 * 16)            // 19,968 A tiles
#define TB_TILES (BB * 5 * 16)             //  7,680 B tiles
#define NT_TILES (TA_TILES + TB_TILES)     // 27,648 tiles (28.3 MB)

#define NSTRIPS_A (BB * 13)    // 1,248
#define NSTRIPS_B (BB * 5)     //   480
#define NSTRIPS   (NSTRIPS_A + NSTRIPS_B)

typedef _Float16 f16x8 __attribute__((ext_vector_type(8)));  // 8 f16 (4 VGPR)
typedef float f4v __attribute__((ext_vector_type(4)));       // MFMA C/D

typedef unsigned int __attribute__((address_space(1))) as1_uint;
typedef unsigned int __attribute__((address_space(3))) as3_uint;

__device__ __forceinline__ void gload_lds16(const void* g, void* l) {
    __builtin_amdgcn_global_load_lds((const as1_uint*)g, (as3_uint*)l, 16, 0, 0);
}

// fp32 -> f16 convert + TILE pass, coalesced BOTH sides (R16's version).
// One 256-thread block per 16-row strip: read 16x512 fp32 contiguous,
// transpose via padded LDS, write the strip's 16 tiles (16 KB) contiguous.
__global__ __launch_bounds__(256) void convert_tiled_kernel(
    const float* __restrict__ img, const float* __restrict__ txt,
    _Float16* __restrict__ dst)
{
    __shared__ _Float16 sh[16 * 520];   // row pad 520 (1040 B = 65x16B)
    const int sid = blockIdx.x;
    const int tid = threadIdx.x;
    const float* base;
    int rowbase, rmax, tile0;
    if (sid < NSTRIPS_A) {
        const int bi = sid / 13, s = sid % 13;
        base = img + (size_t)bi * N1 * DD;
        rowbase = s * 16; rmax = N1 - 1;
        tile0 = sid * 16;
    } else {
        const int bs = sid - NSTRIPS_A;
        const int bt = bs / 5, ct = bs % 5;
        base = txt + (size_t)bt * N2 * DD;
        rowbase = ct * 16; rmax = N2 - 1;
        tile0 = TA_TILES + bs * 16;
    }
#pragma unroll
    for (int it = 0; it < 8; ++it) {
        const int u  = it * 256 + tid;   // 0..2047 float4-units
        const int r  = u >> 7;           // 0..15
        const int c4 = u & 127;          // float4 within row
        int q = rowbase + r; q = q > rmax ? rmax : q;
        float4 v = *(const float4*)(base + (size_t)q * DD + c4 * 4);
        union { _Float16 h[4]; uint2 u2; } o;
        o.h[0] = (_Float16)v.x; o.h[1] = (_Float16)v.y;
        o.h[2] = (_Float16)v.z; o.h[3] = (_Float16)v.w;
        *(uint2*)(sh + r * 520 + c4 * 4) = o.u2;
    }
    __syncthreads();
#pragma unroll
    for (int it = 0; it < 4; ++it) {
        const int w  = it * 256 + tid;   // 0..1023 16B-units
        const int kc = w >> 6;
        const int c  = w & 63;           // cell = lq*16+lm consumed by MFMA
        const int r16 = c & 15, k8 = c >> 4;
        uint4 val = *(const uint4*)(sh + r16 * 520 + kc * 32 + k8 * 8);
        *(uint4*)(dst + (size_t)(tile0 + kc) * 512 + c * 8) = val;
    }
}

// One K=32 sub-step: strips [SG0, SG0+NS) x 5 cts of bt-column CG.
// A strip s at tile s; B ct of column CG at tile 13 + CG*5 + ct.
template <int SG0, int NS, int CG>
__device__ __forceinline__ void compute_sub(const f16x8* __restrict__ fr,
                                            f4v* __restrict__ acc, int lane) {
    f16x8 b[5];
#pragma unroll
    for (int ct = 0; ct < 5; ++ct)
        b[ct] = fr[(ATILES + CG * 5 + ct) * 64 + lane];
#pragma unroll
    for (int i = 0; i < NS; ++i) {
        f16x8 a = fr[(SG0 + i) * 64 + lane];
#pragma unroll
        for (int ct = 0; ct < 5; ++ct)
            acc[i * 5 + ct] = __builtin_amdgcn_mfma_f32_16x16x32_f16(
                a, b[ct], acc[i * 5 + ct], 0, 0, 0);
    }
}

// Reduction partials. C/D layout: col = lane&15, row = (lane>>4)*4 + reg.
// rp[CG*208 + q]: per-bt-column rowmax (wave (g,CG) owns strips of g — the
// full rowmax over bt's 77 cols is exactly this wave's 5 cts).
// cp[g*320 + CG*80 + col]: colmax partial per strip-group, merged over g.
template <int SG0, int NS, int CG>
__device__ __forceinline__ void reduce_phase1(const f4v* __restrict__ acc,
                                              int g, int lq, int lm,
                                              float* __restrict__ rp,
                                              float* __restrict__ cp) {
    float colm[5];
#pragma unroll
    for (int ct = 0; ct < 5; ++ct) colm[ct] = -INFINITY;
#pragma unroll
    for (int i = 0; i < NS; ++i) {
        const int s = SG0 + i;
        float rowm[4] = {-INFINITY, -INFINITY, -INFINITY, -INFINITY};
        bool rows_ok = (s != 12) || (lq == 0);   // rows >=196 are clamp-dups
#pragma unroll
        for (int ct = 0; ct < 5; ++ct) {
            f4v a = acc[i * 5 + ct];
            bool col_ok = (ct != 4) || (lm < N2 - 64);   // cols >=77 dups
            float cm = fmaxf(fmaxf(a[0], a[1]), fmaxf(a[2], a[3]));
            colm[ct] = fmaxf(colm[ct], rows_ok ? cm : -INFINITY);
#pragma unroll
            for (int r = 0; r < 4; ++r)
                rowm[r] = fmaxf(rowm[r], col_ok ? a[r] : -INFINITY);
        }
#pragma unroll
        for (int r = 0; r < 4; ++r) {
            float m = rowm[r];
            m = fmaxf(m, __shfl_xor(m, 1));
            m = fmaxf(m, __shfl_xor(m, 2));
            m = fmaxf(m, __shfl_xor(m, 4));
            m = fmaxf(m, __shfl_xor(m, 8));
            if (lm == 0) rp[CG * 208 + s * 16 + lq * 4 + r] = m;
        }
    }
#pragma unroll
    for (int ct = 0; ct < 5; ++ct) {
        float m = colm[ct];
        m = fmaxf(m, __shfl_xor(m, 16));
        m = fmaxf(m, __shfl_xor(m, 32));
        if (lq == 0) cp[g * 320 + CG * 80 + ct * 16 + lm] = m;
    }
}

// One block per (bi, btQuad): S[208x320] = img[bi].(txt[bt0..bt0+3])^T.
// 1024 threads = 16 waves, 4x4 grid: strip-groups {4,3,3,3} x bt-columns.
// __launch_bounds__(1024,4): 16 waves = 4/SIMD, reg cap 128 — the exact
// cap R6 proved spill-free at this per-wave profile (acc 20 f4v, ~64 VGPR).
template <bool PRE>
__global__ __launch_bounds__(1024, 4) void sim_mfma_kernel(
    const float* __restrict__ imgF, const float* __restrict__ txtF,
    const _Float16* __restrict__ h16,   // TILED (see convert_tiled_kernel)
    float* __restrict__ i2t, float* __restrict__ t2i)
{
    // ---- XCD-locality swizzle (2304 blocks = 8 xcd x 288) ----
    // bi FAST (12 values, A tiles 2.5 MB stay L2-hot), btq SLOW (B quad
    // in flight ~3 x 320 KB). Co-resident working set ~3.4 MB < 4 MB L2.
    const int id  = blockIdx.x;
    const int xcd = id & 7;
    const int lid = id >> 3;             // 0..287
    const int bi  = xcd * 12 + (lid % 12);
    const int btq = lid / 12;            // 0..23
    const int bt0 = btq * 4;

    const int tid = threadIdx.x;
    const int wave = tid >> 6, lane = tid & 63;
    const int lm = lane & 15;
    const int lq = lane >> 4;
    const int g  = wave >> 2;            // strip-group 0..3
    // const int cg = wave & 3;          // bt-column (baked into templates)

    __shared__ __align__(16) _Float16 lds[3 * BUFH];   // 101,376 B
    // epilogue scratch aliases buffer 0: compute(15) reads buffer 15%3=0,
    // but barrier B at the end of iter 15 separates all its readers from
    // the reduction writes below.
    float* scratch = (float*)lds;
    float* rp   = scratch;               //  832: [cg][208] rowmax
    float* cp   = scratch + 832;         // 1280: [g][cg*80+col] colmax part
    float* scol = scratch + 2112;        //  320: merged colmax

    // ---- staging descriptors ----
    // Thread stages cell `lane` of tile T = 16j + wave, j=0..2 (33 tiles:
    // wave 0 stages 3, waves 1-15 stage 2). T<13 -> A strip T; else B:
    // jj=T-13, cg=jj/5, ct=jj%5, bt=bt0+cg. h16 tiled: off = tile*512 +
    // lane*8; stage adds kc*512 (adjacent kc tiles -> contiguous 1 KB).
    int off[3];
    const float* fsrc[3];
#pragma unroll
    for (int j = 0; j < 3; ++j) {
        const int T = 16 * j + wave;
        if constexpr (PRE) {
            int t = 0;
            if (T < ATILES) {
                t = (bi * 13 + T) * 16;
            } else if (T < NTILES) {
                const int jj = T - ATILES;     // 0..19
                const int cgj = jj / 5, ct = jj % 5;
                const int bt = bt0 + cgj;
                t = TA_TILES + (bt * 5 + ct) * 16;
            }
            off[j] = t * 512 + lane * 8;
        } else {
            int o = 0;
            bool isA = true;
            if (T < ATILES) {
                int q = T * 16 + lm; q = q > (N1 - 1) ? (N1 - 1) : q;
                o = (bi * N1 + q) * DD + lq * 8;
            } else if (T < NTILES) {
                isA = false;
                const int jj = T - ATILES;
                const int cgj = jj / 5, ct = jj % 5;
                const int bt = bt0 + cgj;
                int r = ct * 16 + lm; r = r > (N2 - 1) ? (N2 - 1) : r;
                o = (bt * N2 + r) * DD + lq * 8;
            }
            off[j] = o;
            fsrc[j] = isA ? imgF : txtF;
        }
    }

    // async staging of K32 chunk kc into buffer b (contiguous 1-KB reads)
    auto stage = [&](int kc, int b) {
        const int k0 = kc * 512;
#pragma unroll
        for (int j = 0; j < 3; ++j)
            if (16 * j + wave < NTILES)   // wave-uniform guard
                gload_lds16(h16 + off[j] + k0,
                            lds + (b * NTILES + 16 * j + wave) * 512);
    };

    f4v acc[20];   // strip-group 0 waves: 20; others: 15 (tail dead)
#pragma unroll
    for (int i = 0; i < 20; ++i) acc[i] = (f4v){0.f, 0.f, 0.f, 0.f};

    auto do_compute = [&](const f16x8* fr) {
        if      (wave ==  0) compute_sub<0, 4, 0>(fr, acc, lane);
        else if (wave ==  1) compute_sub<0, 4, 1>(fr, acc, lane);
        else if (wave ==  2) compute_sub<0, 4, 2>(fr, acc, lane);
        else if (wave ==  3) compute_sub<0, 4, 3>(fr, acc, lane);
        else if (wave ==  4) compute_sub<4, 3, 0>(fr, acc, lane);
        else if (wave ==  5) compute_sub<4, 3, 1>(fr, acc, lane);
        else if (wave ==  6) compute_sub<4, 3, 2>(fr, acc, lane);
        else if (wave ==  7) compute_sub<4, 3, 3>(fr, acc, lane);
        else if (wave ==  8) compute_sub<7, 3, 0>(fr, acc, lane);
        else if (wave ==  9) compute_sub<7, 3, 1>(fr, acc, lane);
        else if (wave == 10) compute_sub<7, 3, 2>(fr, acc, lane);
        else if (wave == 11) compute_sub<7, 3, 3>(fr, acc, lane);
        else if (wave == 12) compute_sub<10, 3, 0>(fr, acc, lane);
        else if (wave == 13) compute_sub<10, 3, 1>(fr, acc, lane);
        else if (wave == 14) compute_sub<10, 3, 2>(fr, acc, lane);
        else                 compute_sub<10, 3, 3>(fr, acc, lane);
    };

    if constexpr (PRE) {
        // ---- K loop: 16 steps of BK=32, 3 buffers, prefetch distance 2.
        // Counted vmcnt per wave (wave 0 holds 3 loads/step, others 2):
        // steady state 3 steps in flight -> wait oldest: vmcnt(2L).
        // Barrier A: all waves' loads for buf kc landed.
        // Barrier B: all waves done reading buf kc%3 before stage(kc+3)
        // (issued at iter kc+1 top) overwrites it.
        stage(0, 0);
        stage(1, 1);
#pragma unroll 1
        for (int kc = 0; kc < 16; ++kc) {
            if (kc < 14) {
                stage(kc + 2, (kc + 2) % 3);
                if (wave == 0) asm volatile("s_waitcnt vmcnt(6)" ::: "memory");
                else           asm volatile("s_waitcnt vmcnt(4)" ::: "memory");
            } else if (kc == 14) {
                if (wave == 0) asm volatile("s_waitcnt vmcnt(3)" ::: "memory");
                else           asm volatile("s_waitcnt vmcnt(2)" ::: "memory");
            } else {
                asm volatile("s_waitcnt vmcnt(0)" ::: "memory");
            }
            __builtin_amdgcn_s_barrier();          // A
            asm volatile("" ::: "memory");
            do_compute((const f16x8*)(lds + (kc % 3) * BUFH));
            asm volatile("" ::: "memory");
            __builtin_amdgcn_s_barrier();          // B
        }
    } else {
        // correctness fallback (workspace too small): sync single-buffer
#pragma unroll 1
        for (int kc = 0; kc < 16; ++kc) {
            __syncthreads();
            const int k0 = kc * 32;
#pragma unroll
            for (int j = 0; j < 3; ++j) {
                const int T = 16 * j + wave;
                if (T < NTILES) {
                    float4 v0 = *(const float4*)(fsrc[j] + off[j] + k0);
                    float4 v1 = *(const float4*)(fsrc[j] + off[j] + k0 + 4);
                    union { f16x8 f; uint4 u; } o;
                    o.f[0] = (_Float16)v0.x; o.f[1] = (_Float16)v0.y;
                    o.f[2] = (_Float16)v0.z; o.f[3] = (_Float16)v0.w;
                    o.f[4] = (_Float16)v1.x; o.f[5] = (_Float16)v1.y;
                    o.f[6] = (_Float16)v1.z; o.f[7] = (_Float16)v1.w;
                    ((uint4*)lds)[T * 64 + lane] = o.u;
                }
            }
            __syncthreads();
            do_compute((const f16x8*)lds);
        }
        __syncthreads();
    }

    // ---- fused reductions (buffer-0 scratch; barrier-separated) ----
    if      (wave ==  0) reduce_phase1<0, 4, 0>(acc, g, lq, lm, rp, cp);
    else if (wave ==  1) reduce_phase1<0, 4, 1>(acc, g, lq, lm, rp, cp);
    else if (wave ==  2) reduce_phase1<0, 4, 2>(acc, g, lq, lm, rp, cp);
    else if (wave ==  3) reduce_phase1<0, 4, 3>(acc, g, lq, lm, rp, cp);
    else if (wave ==  4) reduce_phase1<4, 3, 0>(acc, g, lq, lm, rp, cp);
    else if (wave ==  5) reduce_phase1<4, 3, 1>(acc, g, lq, lm, rp, cp);
    else if (wave ==  6) reduce_phase1<4, 3, 2>(acc, g, lq, lm, rp, cp);
    else if (wave ==  7) reduce_phase1<4, 3, 3>(acc, g, lq, lm, rp, cp);
    else if (wave ==  8) reduce_phase1<7, 3, 0>(acc, g, lq, lm, rp, cp);
    else if (wave ==  9) reduce_phase1<7, 3, 1>(acc, g, lq, lm, rp, cp);
    else if (wave == 10) reduce_phase1<7, 3, 2>(acc, g, lq, lm, rp, cp);
    else if (wave == 11) reduce_phase1<7, 3, 3>(acc, g, lq, lm, rp, cp);
    else if (wave == 12) reduce_phase1<10, 3, 0>(acc, g, lq, lm, rp, cp);
    else if (wave == 13) reduce_phase1<10, 3, 1>(acc, g, lq, lm, rp, cp);
    else if (wave == 14) reduce_phase1<10, 3, 2>(acc, g, lq, lm, rp, cp);
    else                 reduce_phase1<10, 3, 3>(acc, g, lq, lm, rp, cp);
    __syncthreads();

    // i2t: waves 0-3, one per bt-column: mean over q<196 of rp[cg][q].
    if (wave < 4) {
        const float* r = rp + wave * 208;
        float v = r[lane] + r[64 + lane] + r[128 + lane]
                + ((lane < 4) ? r[192 + lane] : 0.f);
        v += __shfl_xor(v, 1);  v += __shfl_xor(v, 2);  v += __shfl_xor(v, 4);
        v += __shfl_xor(v, 8);  v += __shfl_xor(v, 16); v += __shfl_xor(v, 32);
        if (lane == 0) i2t[bi * BB + bt0 + wave] = v * (1.f / (float)N1);
    }
    // colmax merge across the 4 strip-groups
    if (tid < 320)
        scol[tid] = fmaxf(fmaxf(cp[tid], cp[320 + tid]),
                          fmaxf(cp[640 + tid], cp[960 + tid]));
    __syncthreads();
    // t2i: waves 4-7, one per bt-column: mean over r<77 of merged colmax.
    if (wave >= 4 && wave < 8) {
        const int c4 = wave - 4;
        const float* c = scol + c4 * 80;
        float cv = c[lane] + ((lane < N2 - 64) ? c[64 + lane] : 0.f);
        cv += __shfl_xor(cv, 1);  cv += __shfl_xor(cv, 2);  cv += __shfl_xor(cv, 4);
        cv += __shfl_xor(cv, 8);  cv += __shfl_xor(cv, 16); cv += __shfl_xor(cv, 32);
        if (lane == 0)
            t2i[(bt0 + c4) * BB + bi] = cv * (1.f / (float)N2);
    }
}

// CE with arange labels over both [B,B] logit matrices.
__global__ __launch_bounds__(256) void ce_kernel(
    const float* __restrict__ i2t, const float* __restrict__ t2i,
    float* __restrict__ out)
{
    const int tid = threadIdx.x;
    const int wid = tid >> 6;
    const int lane = tid & 63;

    float contrib = 0.f;
    if (tid < 2 * BB) {
        const float* M = (tid < BB) ? i2t : t2i;
        const int b = (tid < BB) ? tid : tid - BB;
        const float* row = M + b * BB;
        float mx = row[0];
#pragma unroll 1
        for (int c = 1; c < BB; ++c) mx = fmaxf(mx, row[c]);
        float s = 0.f;
#pragma unroll 1
        for (int c = 0; c < BB; ++c) s += expf(row[c] - mx);
        float lse = mx + logf(s);
        contrib = row[b] - lse;
    }
    contrib += __shfl_xor(contrib, 1);
    contrib += __shfl_xor(contrib, 2);
    contrib += __shfl_xor(contrib, 4);
    contrib += __shfl_xor(contrib, 8);
    contrib += __shfl_xor(contrib, 16);
    contrib += __shfl_xor(contrib, 32);

    __shared__ float s_part[4];
    if (lane == 0) s_part[wid] = contrib;
    __syncthreads();
    if (tid == 0) {
        float total = s_part[0] + s_part[1] + s_part[2] + s_part[3];
        out[0] = -total * (1.f / (float)(2 * BB));
    }
}

extern "C" void kernel_launch(void* const* d_in, const int* in_sizes, int n_in,
                              void* d_out, int out_size, void* d_ws, size_t ws_size,
                              hipStream_t stream) {
    const float* img = (const float*)d_in[0];   // [96,196,512] fp32
    const float* txt = (const float*)d_in[1];   // [96,77,512] fp32
    float* i2t = (float*)d_ws;                  // [96,96]
    float* t2i = i2t + BB * BB;                 // [96,96]

    const size_t conv_off = 2 * BB * BB * sizeof(float);   // 16B-aligned
    const size_t need = conv_off + (size_t)NT_TILES * 512 * sizeof(_Float16);

    const int nblocks = BB * (BB / 4);   // 2304 = (bi, btQuad)
    if (ws_size >= need) {
        _Float16* h16 = (_Float16*)((char*)d_ws + conv_off);
        convert_tiled_kernel<<<NSTRIPS, 256, 0, stream>>>(img, txt, h16);
        sim_mfma_kernel<true><<<nblocks, 1024, 0, stream>>>(img, txt, h16, i2t, t2i);
    } else {
        sim_mfma_kernel<false><<<nblocks, 1024, 0, stream>>>(img, txt, nullptr, i2t, t2i);
    }
    ce_kernel<<<1, 256, 0, stream>>>(i2t, t2i, (float*)d_out);
}

// Round 10
// 281.030 us; speedup vs baseline: 1.1010x; 1.0778x over previous
//
#include <hip/hip_runtime.h>
#include <math.h>

// FineGrainLoss: B=96, n1=196 (image tokens), n2=77 (text tokens), d=512.
#define BB 96
#define N1 196
#define N2 77
#define DD 512

#define IMGN (BB * N1 * DD)
#define TXTN (BB * N2 * DD)

// R19 B-FROM-GLOBAL: champion R6 structure (4608 blocks, 512 thr, 8 waves
// 4x2, tile 208x160, BK=32, 3 LDS buffers, prefetch dist 2, 2 barriers per
// step, tiled h16, 2 blocks/CU) but B fragments are loaded STRAIGHT FROM
// GLOBAL into VGPRs (5 x global_load_dwordx4/wave/step, coalesced 1-KB,
// L2-hot) and only A tiles are staged through LDS.
// WHY: R6 slot model (3,275 cyc): LDS port 1,960 cyc (132 ds_read_b128 +
// DMA writes) is the top consumer; B was 40/66 reads + 10/23 staged KB.
// Removing B: LDS port ~830 cyc; B loads are barrier-free reads hidden by
// 16 waves/CU + the independent co-resident block (R9 lesson: 2 blocks is
// load-bearing). Issue order: b-loads BEFORE stage(kc+2), so compiler's
// wait before b-use is vmcnt(L) and never drains the A-prefetch.
// LESSONS: (R11) never force occupancy via launch_bounds (acc spills ->
// WRITE_SIZE balloons). (R14) +36 staging regs spilled; here +20 only.
// (R7/R9) keep 16 waves/CU as 2 independent 8-wave blocks. (R17) swizzle
// must keep co-resident working set < 4 MB L2 — watch FETCH_SIZE.
#define ATILES 13
#define NTILES 13              // A only in LDS now
#define BUFH (NTILES * 512)    // _Float16 per buffer (6,656 f16 = 13,312 B)

#define TA_TILES (BB * 13 * 16)            // 19,968 A tiles
#define TB_TILES (BB * 5 * 16)             //  7,680 B tiles
#define NT_TILES (TA_TILES + TB_TILES)     // 27,648 tiles (28.3 MB)

#define NSTRIPS_A (BB * 13)    // 1,248
#define NSTRIPS_B (BB * 5)     //   480
#define NSTRIPS   (NSTRIPS_A + NSTRIPS_B)

typedef _Float16 f16x8 __attribute__((ext_vector_type(8)));  // 8 f16 (4 VGPR)
typedef float f4v __attribute__((ext_vector_type(4)));       // MFMA C/D

typedef unsigned int __attribute__((address_space(1))) as1_uint;
typedef unsigned int __attribute__((address_space(3))) as3_uint;

__device__ __forceinline__ void gload_lds16(const void* g, void* l) {
    __builtin_amdgcn_global_load_lds((const as1_uint*)g, (as3_uint*)l, 16, 0, 0);
}

// fp32 -> f16 convert + TILE pass, coalesced BOTH sides (R16's version).
// One 256-thread block per 16-row strip: read 16x512 fp32 contiguous,
// transpose via padded LDS, write the strip's 16 tiles (16 KB) contiguous.
__global__ __launch_bounds__(256) void convert_tiled_kernel(
    const float* __restrict__ img, const float* __restrict__ txt,
    _Float16* __restrict__ dst)
{
    __shared__ _Float16 sh[16 * 520];   // row pad 520 (1040 B = 65x16B)
    const int sid = blockIdx.x;
    const int tid = threadIdx.x;
    const float* base;
    int rowbase, rmax, tile0;
    if (sid < NSTRIPS_A) {
        const int bi = sid / 13, s = sid % 13;
        base = img + (size_t)bi * N1 * DD;
        rowbase = s * 16; rmax = N1 - 1;
        tile0 = sid * 16;
    } else {
        const int bs = sid - NSTRIPS_A;
        const int bt = bs / 5, ct = bs % 5;
        base = txt + (size_t)bt * N2 * DD;
        rowbase = ct * 16; rmax = N2 - 1;
        tile0 = TA_TILES + bs * 16;
    }
#pragma unroll
    for (int it = 0; it < 8; ++it) {
        const int u  = it * 256 + tid;   // 0..2047 float4-units
        const int r  = u >> 7;           // 0..15
        const int c4 = u & 127;          // float4 within row
        int q = rowbase + r; q = q > rmax ? rmax : q;
        float4 v = *(const float4*)(base + (size_t)q * DD + c4 * 4);
        union { _Float16 h[4]; uint2 u2; } o;
        o.h[0] = (_Float16)v.x; o.h[1] = (_Float16)v.y;
        o.h[2] = (_Float16)v.z; o.h[3] = (_Float16)v.w;
        *(uint2*)(sh + r * 520 + c4 * 4) = o.u2;
    }
    __syncthreads();
#pragma unroll
    for (int it = 0; it < 4; ++it) {
        const int w  = it * 256 + tid;   // 0..1023 16B-units
        const int kc = w >> 6;
        const int c  = w & 63;           // cell = lq*16+lm consumed by MFMA
        const int r16 = c & 15, k8 = c >> 4;
        uint4 val = *(const uint4*)(sh + r16 * 520 + kc * 32 + k8 * 8);
        *(uint4*)(dst + (size_t)(tile0 + kc) * 512 + c * 8) = val;
    }
}

// One K=32 sub-step: strips [SG0, SG0+NS) x 5 B-frags (already in VGPRs).
template <int SG0, int NS>
__device__ __forceinline__ void compute_sub(const f16x8* __restrict__ fr,
                                            const f16x8* __restrict__ b,
                                            f4v* __restrict__ acc, int lane) {
#pragma unroll
    for (int i = 0; i < NS; ++i) {
        f16x8 a = fr[(SG0 + i) * 64 + lane];
#pragma unroll
        for (int ct = 0; ct < 5; ++ct)
            acc[i * 5 + ct] = __builtin_amdgcn_mfma_f32_16x16x32_f16(
                a, b[ct], acc[i * 5 + ct], 0, 0, 0);
    }
}

// Reduction partials. C/D layout: col = lane&15, row = (lane>>4)*4 + reg.
// rp[H*208 + q]: per-bt-half rowmax (each (H, strip) owned by one wave).
// cp[g*160 + H*80 + col]: colmax partial per strip-group.
template <int SG0, int NS, int H>
__device__ __forceinline__ void reduce_phase1(const f4v* __restrict__ acc,
                                              int g, int lq, int lm,
                                              float* __restrict__ rp,
                                              float* __restrict__ cp) {
    float colm[5];
#pragma unroll
    for (int ct = 0; ct < 5; ++ct) colm[ct] = -INFINITY;
#pragma unroll
    for (int i = 0; i < NS; ++i) {
        const int s = SG0 + i;
        float rowm[4] = {-INFINITY, -INFINITY, -INFINITY, -INFINITY};
        bool rows_ok = (s != 12) || (lq == 0);   // rows >=196 are clamp-dups
#pragma unroll
        for (int ct = 0; ct < 5; ++ct) {
            f4v a = acc[i * 5 + ct];
            bool col_ok = (ct != 4) || (lm < N2 - 64);   // cols >=77 dups
            float cm = fmaxf(fmaxf(a[0], a[1]), fmaxf(a[2], a[3]));
            colm[ct] = fmaxf(colm[ct], rows_ok ? cm : -INFINITY);
#pragma unroll
            for (int r = 0; r < 4; ++r)
                rowm[r] = fmaxf(rowm[r], col_ok ? a[r] : -INFINITY);
        }
#pragma unroll
        for (int r = 0; r < 4; ++r) {
            float m = rowm[r];
            m = fmaxf(m, __shfl_xor(m, 1));
            m = fmaxf(m, __shfl_xor(m, 2));
            m = fmaxf(m, __shfl_xor(m, 4));
            m = fmaxf(m, __shfl_xor(m, 8));
            if (lm == 0) rp[H * 208 + s * 16 + lq * 4 + r] = m;
        }
    }
#pragma unroll
    for (int ct = 0; ct < 5; ++ct) {
        float m = colm[ct];
        m = fmaxf(m, __shfl_xor(m, 16));
        m = fmaxf(m, __shfl_xor(m, 32));
        if (lq == 0) cp[g * 160 + H * 80 + ct * 16 + lm] = m;
    }
}

// One block per (bi, btPair): S[208x160] = img[bi].(txt[bt0]|txt[bt1])^T.
// 512 threads = 8 waves in a 4x2 grid: strip-groups {4,3,3,3} x bt-half.
// __launch_bounds__(512,4): total-reg cap 128/wave -> no spill (acc 80 f32
// + 20 b-frag VGPR + ~45 addr). Do NOT raise the min-waves arg (R11).
template <bool PRE>
__global__ __launch_bounds__(512, 4) void sim_mfma_kernel(
    const float* __restrict__ imgF, const float* __restrict__ txtF,
    const _Float16* __restrict__ h16,   // TILED (see convert_tiled_kernel)
    float* __restrict__ i2t, float* __restrict__ t2i)
{
    // ---- XCD-locality swizzle (4608 blocks = 8 xcd x 12 bi x 48 btPairs),
    // R6's proven layout (FETCH 47 MB) ----
    const int id  = blockIdx.x;
    const int xcd = id & 7;
    const int lid = id >> 3;           // 0..575
    const int w   = lid % 48;
    const int btq = lid / 48;          // 0..11
    const int btp = btq * 4 + (w & 3); // 0..47
    const int bi  = xcd * 12 + (w >> 2);
    const int bt0 = btp * 2;

    const int tid = threadIdx.x;
    const int wave = tid >> 6, lane = tid & 63;
    const int lm = lane & 15;
    const int lq = lane >> 4;
    const int g = wave >> 1;           // strip-group 0..3
    const int h = wave & 1;            // bt-half

    __shared__ __align__(16) _Float16 lds[3 * BUFH];   // 39,936 B
    // epilogue scratch aliases buffer 0: compute(15) reads buffer 15%3=0,
    // but barrier B at the end of iter 15 separates its readers from the
    // reduction writes below.
    float* rp   = (float*)lds;           // 416: [half][208] rowmax
    float* cp   = (float*)lds + 416;     // 640: [g][160] colmax partials
    float* sws  = (float*)lds + 1056;    // 8
    float* scol = (float*)lds + 1064;    // 160

    // ---- A staging descriptors (tiled h16) ----
    // Wave stages tile T=wave (all) and T=8+wave (waves 0-4): 13 A tiles.
    int offA0 = 0, offA1 = 0;
    const float* fA0; const float* fA1;
    if constexpr (PRE) {
        offA0 = ((bi * 13 + wave) * 16) * 512 + lane * 8;
        if (wave < 5) offA1 = ((bi * 13 + 8 + wave) * 16) * 512 + lane * 8;
    } else {
        int q0 = wave * 16 + lm; q0 = q0 > (N1 - 1) ? (N1 - 1) : q0;
        offA0 = (bi * N1 + q0) * DD + lq * 8;
        fA0 = imgF;
        int q1 = (8 + wave) * 16 + lm; q1 = q1 > (N1 - 1) ? (N1 - 1) : q1;
        offA1 = (bi * N1 + q1) * DD + lq * 8;
        fA1 = imgF;
    }

    // B fragment base (tiled h16): frag(ct, kc) at gb[ct*1024 + kc*64].
    const f16x8* gb = nullptr;
    if constexpr (PRE)
        gb = (const f16x8*)h16 + (TA_TILES + (bt0 + h) * 5 * 16) * 64 + lane;

    auto stage = [&](int kc, int b) {
        const int k0 = kc * 512;
        gload_lds16(h16 + offA0 + k0, lds + (b * NTILES + wave) * 512);
        if (wave < 5)
            gload_lds16(h16 + offA1 + k0, lds + (b * NTILES + 8 + wave) * 512);
    };

    f4v acc[20];   // waves 0,1 (4-strip group): 20; others: 15 (tail dead)
#pragma unroll
    for (int i = 0; i < 20; ++i) acc[i] = (f4v){0.f, 0.f, 0.f, 0.f};

    auto do_compute = [&](const f16x8* fr, const f16x8* b) {
        if (wave == 0 || wave == 1)      compute_sub<0, 4>(fr, b, acc, lane);
        else if (wave == 2 || wave == 3) compute_sub<4, 3>(fr, b, acc, lane);
        else if (wave == 4 || wave == 5) compute_sub<7, 3>(fr, b, acc, lane);
        else                             compute_sub<10, 3>(fr, b, acc, lane);
    };

    if constexpr (PRE) {
        // ---- K loop: 16 steps of BK=32, A in 3 LDS buffers (prefetch
        // dist 2, counted vmcnt), B straight to VGPRs each step.
        // Per-iter issue order (the order IS the correctness of the
        // pipeline): b-loads(kc) FIRST, then stage(kc+2) — so the
        // compiler's wait before the first b use is vmcnt(L) (only
        // stage(kc+2) younger) and never drains the in-flight stages.
        // Guard before barrier A: ensure stage(kc) done. Outstanding =
        // stage(kc+1):L + b(kc):5 + stage(kc+2):L -> vmcnt(2L+5) = 9/7.
        stage(0, 0);
        stage(1, 1);
#pragma unroll 1
        for (int kc = 0; kc < 16; ++kc) {
            f16x8 bfr[5];
#pragma unroll
            for (int ct = 0; ct < 5; ++ct)
                bfr[ct] = gb[ct * 1024 + kc * 64];
            if (kc + 2 < 16) stage(kc + 2, (kc + 2) % 3);
            if (wave < 5) asm volatile("s_waitcnt vmcnt(9)" ::: "memory");
            else          asm volatile("s_waitcnt vmcnt(7)" ::: "memory");
            __builtin_amdgcn_s_barrier();          // A: A-tiles for kc ready
            asm volatile("" ::: "memory");
            do_compute((const f16x8*)(lds + (kc % 3) * BUFH), bfr);
            asm volatile("" ::: "memory");
            __builtin_amdgcn_s_barrier();          // B: buf free for reuse
        }
    } else {
        // correctness fallback (workspace too small): single-buffer A with
        // on-the-fly convert; B converted straight to registers.
        const int btf = bt0 + h;
#pragma unroll 1
        for (int kc = 0; kc < 16; ++kc) {
            __syncthreads();
            const int k0 = kc * 32;
#pragma unroll
            for (int j = 0; j < 2; ++j) {
                const int T = j * 8 + wave;
                if (j == 0 || wave < 5) {
                    const float* src = (j ? fA1 : fA0) + (j ? offA1 : offA0) + k0;
                    float4 v0 = *(const float4*)(src);
                    float4 v1 = *(const float4*)(src + 4);
                    union { f16x8 f; uint4 u; } o;
                    o.f[0] = (_Float16)v0.x; o.f[1] = (_Float16)v0.y;
                    o.f[2] = (_Float16)v0.z; o.f[3] = (_Float16)v0.w;
                    o.f[4] = (_Float16)v1.x; o.f[5] = (_Float16)v1.y;
                    o.f[6] = (_Float16)v1.z; o.f[7] = (_Float16)v1.w;
                    ((uint4*)lds)[T * 64 + lane] = o.u;
                }
            }
            __syncthreads();
            f16x8 bfr[5];
#pragma unroll
            for (int ct = 0; ct < 5; ++ct) {
                int r = ct * 16 + lm; r = r > (N2 - 1) ? (N2 - 1) : r;
                const float* src = txtF + (btf * N2 + r) * DD + k0 + lq * 8;
                float4 v0 = *(const float4*)(src);
                float4 v1 = *(const float4*)(src + 4);
                f16x8 f;
                f[0] = (_Float16)v0.x; f[1] = (_Float16)v0.y;
                f[2] = (_Float16)v0.z; f[3] = (_Float16)v0.w;
                f[4] = (_Float16)v1.x; f[5] = (_Float16)v1.y;
                f[6] = (_Float16)v1.z; f[7] = (_Float16)v1.w;
                bfr[ct] = f;
            }
            do_compute((const f16x8*)lds, bfr);
        }
        __syncthreads();
    }

    // ---- fused reductions (buffer-0 scratch; barrier-separated) ----
    if (wave == 0)      reduce_phase1<0, 4, 0>(acc, g, lq, lm, rp, cp);
    else if (wave == 1) reduce_phase1<0, 4, 1>(acc, g, lq, lm, rp, cp);
    else if (wave == 2) reduce_phase1<4, 3, 0>(acc, g, lq, lm, rp, cp);
    else if (wave == 3) reduce_phase1<4, 3, 1>(acc, g, lq, lm, rp, cp);
    else if (wave == 4) reduce_phase1<7, 3, 0>(acc, g, lq, lm, rp, cp);
    else if (wave == 5) reduce_phase1<7, 3, 1>(acc, g, lq, lm, rp, cp);
    else if (wave == 6) reduce_phase1<10, 3, 0>(acc, g, lq, lm, rp, cp);
    else                reduce_phase1<10, 3, 1>(acc, g, lq, lm, rp, cp);
    __syncthreads();

    // i2t: mean over q<196 of rowmax, per bt-half.
    // Waves 0-3 (tid 0-255) cover half 0; waves 4-7 cover half 1.
    {
        const int half = tid >> 8;
        const int t = tid & 255;
        float v = (t < N1) ? rp[half * 208 + t] : 0.f;
        v += __shfl_xor(v, 1);  v += __shfl_xor(v, 2);  v += __shfl_xor(v, 4);
        v += __shfl_xor(v, 8);  v += __shfl_xor(v, 16); v += __shfl_xor(v, 32);
        if (lane == 0) sws[wave] = v;
    }
    // colmax merge across strip-groups
    if (tid < 160) {
        float m = fmaxf(fmaxf(cp[tid], cp[160 + tid]),
                        fmaxf(cp[320 + tid], cp[480 + tid]));
        scol[tid] = m;
    }
    __syncthreads();
    if (tid == 0)
        i2t[bi * BB + bt0] =
            (sws[0] + sws[1] + sws[2] + sws[3]) * (1.f / (float)N1);
    if (tid == 1)
        i2t[bi * BB + bt0 + 1] =
            (sws[4] + sws[5] + sws[6] + sws[7]) * (1.f / (float)N1);
    // t2i: mean over r<77 of colmax; wave0 -> bt0 (cols 0-79), wave1 -> bt1.
    if (wave < 2) {
        const float* c = scol + wave * 80;
        float cv = c[lane] + ((lane < N2 - 64) ? c[64 + lane] : 0.f);
        cv += __shfl_xor(cv, 1);  cv += __shfl_xor(cv, 2);  cv += __shfl_xor(cv, 4);
        cv += __shfl_xor(cv, 8);  cv += __shfl_xor(cv, 16); cv += __shfl_xor(cv, 32);
        if (lane == 0)
            t2i[(bt0 + wave) * BB + bi] = cv * (1.f / (float)N2);
    }
}

// CE with arange labels, parallelized: 16 waves x 12 rows, wave-parallel
// max/sum via shuffles (old 1-block serial-96 version was latency-bound).
__global__ __launch_bounds__(1024) void ce_kernel(
    const float* __restrict__ i2t, const float* __restrict__ t2i,
    float* __restrict__ out)
{
    const int tid = threadIdx.x;
    const int wave = tid >> 6;
    const int lane = tid & 63;

    float total = 0.f;
#pragma unroll 1
    for (int rr = 0; rr < 12; ++rr) {
        const int row = rr * 16 + wave;        // 0..191
        const float* M = (row < BB) ? i2t : t2i;
        const int b = (row < BB) ? row : row - BB;
        const float* r = M + b * BB;
        float a = r[lane];
        float c = (lane < BB - 64) ? r[64 + lane] : -INFINITY;
        float m = fmaxf(a, c);
        m = fmaxf(m, __shfl_xor(m, 1));  m = fmaxf(m, __shfl_xor(m, 2));
        m = fmaxf(m, __shfl_xor(m, 4));  m = fmaxf(m, __shfl_xor(m, 8));
        m = fmaxf(m, __shfl_xor(m, 16)); m = fmaxf(m, __shfl_xor(m, 32));
        float s = expf(a - m) + ((lane < BB - 64) ? expf(c - m) : 0.f);
        s += __shfl_xor(s, 1);  s += __shfl_xor(s, 2);  s += __shfl_xor(s, 4);
        s += __shfl_xor(s, 8);  s += __shfl_xor(s, 16); s += __shfl_xor(s, 32);
        total += r[b] - (m + logf(s));
    }
    __shared__ float sp[16];
    if (lane == 0) sp[wave] = total;
    __syncthreads();
    if (tid == 0) {
        float t = 0.f;
#pragma unroll
        for (int i = 0; i < 16; ++i) t += sp[i];
        out[0] = -t * (1.f / (float)(2 * BB));
    }
}

extern "C" void kernel_launch(void* const* d_in, const int* in_sizes, int n_in,
                              void* d_out, int out_size, void* d_ws, size_t ws_size,
                              hipStream_t stream) {
    const float* img = (const float*)d_in[0];   // [96,196,512] fp32
    const float* txt = (const float*)d_in[1];   // [96,77,512] fp32
    float* i2t = (float*)d_ws;                  // [96,96]
    float* t2i = i2t + BB * BB;                 // [96,96]

    const size_t conv_off = 2 * BB * BB * sizeof(float);   // 16B-aligned
    const size_t need = conv_off + (size_t)NT_TILES * 512 * sizeof(_Float16);

    const int nblocks = BB * (BB / 2);   // 4608 = (bi, btPair)
    if (ws_size >= need) {
        _Float16* h16 = (_Float16*)((char*)d_ws + conv_off);
        convert_tiled_kernel<<<NSTRIPS, 256, 0, stream>>>(img, txt, h16);
        sim_mfma_kernel<true><<<nblocks, 512, 0, stream>>>(img, txt, h16, i2t, t2i);
    } else {
        sim_mfma_kernel<false><<<nblocks, 512, 0, stream>>>(img, txt, nullptr, i2t, t2i);
    }
    ce_kernel<<<1, 1024, 0, stream>>>(i2t, t2i, (float*)d_out);
}